// Round 7
// baseline (264.354 us; speedup 1.0000x reference)
//
#include <hip/hip_runtime.h>

// QRNN forget-mult: h_t = i_t*z_t + f_t*h_{t-1}, T=4096, B=32, H=256, fp32.
// Chunked parallel scan over T.
// Round 7: TLP, not ILP. R4->R6 falsified the ILP theory (VGPR 36->68, BW flat
// at 1.7 TB/s, occupancy 20%). Fix: NC=256 chunks -> 2048 blocks = 32 waves/CU,
// and keep VGPR <= 64 (U=2, __launch_bounds__(256,8)) so occupancy isn't
// register-capped (waves/CU halve at 64/128/256 VGPR).

constexpr int T   = 4096;
constexpr int CHN = 32 * 256;   // 8192 channels (B*H)
constexpr int C4  = CHN / 4;    // 2048 float4-channels

typedef float v4f __attribute__((ext_vector_type(4)));

__device__ __forceinline__ void fma4(float4& h, const float4& ft, const float4& zt,
                                     const float4& it) {
  h.x = fmaf(ft.x, h.x, it.x * zt.x);
  h.y = fmaf(ft.y, h.y, it.y * zt.y);
  h.z = fmaf(ft.z, h.z, it.z * zt.z);
  h.w = fmaf(ft.w, h.w, it.w * zt.w);
}

// ---------------- kernel 1: per-chunk local recurrence + forget product ----------------
template <int NC, int U>
__global__ __launch_bounds__(256, 8) void qrnn_partial(
    const float4* __restrict__ f, const float4* __restrict__ z,
    const float4* __restrict__ ig,
    float4* __restrict__ Ps, float4* __restrict__ Hs) {
  constexpr int CL = T / NC;
  static_assert(CL % U == 0, "");
  const int c4    = blockIdx.x * 256 + threadIdx.x;
  const int chunk = blockIdx.y;
  int idx = chunk * CL * C4 + c4;
  float4 h = make_float4(0.f, 0.f, 0.f, 0.f);
  float4 P = make_float4(1.f, 1.f, 1.f, 1.f);
  for (int body = 0; body < CL / U; ++body) {
    float4 rf[U], rz[U], ri[U];
#pragma unroll
    for (int u = 0; u < U; ++u) {
      rf[u] = f[idx + u * C4];
      rz[u] = z[idx + u * C4];
      ri[u] = ig[idx + u * C4];
    }
#pragma unroll
    for (int u = 0; u < U; ++u) {
      fma4(h, rf[u], rz[u], ri[u]);
      P.x *= rf[u].x; P.y *= rf[u].y; P.z *= rf[u].z; P.w *= rf[u].w;
    }
    idx += U * C4;
  }
  Ps[chunk * C4 + c4] = P;
  Hs[chunk * C4 + c4] = h;
}

// ---------------- kernel 2: sequential scan over chunk summaries ----------------
// After this kernel, Hs[k] holds the hidden state ENTERING chunk k.
template <int NC>
__global__ __launch_bounds__(256) void qrnn_scan(
    const float4* __restrict__ hinit,
    const float4* __restrict__ Ps, float4* __restrict__ Hs) {
  const int c4 = blockIdx.x * 256 + threadIdx.x;
  float4 carry = hinit[c4];
  constexpr int US = 8;
  for (int k0 = 0; k0 < NC; k0 += US) {
    float4 rp[US], rh[US];
#pragma unroll
    for (int u = 0; u < US; ++u) {
      rp[u] = Ps[(k0 + u) * C4 + c4];
      rh[u] = Hs[(k0 + u) * C4 + c4];
    }
#pragma unroll
    for (int u = 0; u < US; ++u) {
      Hs[(k0 + u) * C4 + c4] = carry;
      carry.x = fmaf(rp[u].x, carry.x, rh[u].x);
      carry.y = fmaf(rp[u].y, carry.y, rh[u].y);
      carry.z = fmaf(rp[u].z, carry.z, rh[u].z);
      carry.w = fmaf(rp[u].w, carry.w, rh[u].w);
    }
  }
}

// ---------------- kernel 3: recompute chunk from exact carry, write output ----------------
template <int NC, int U>
__global__ __launch_bounds__(256, 8) void qrnn_final(
    const float4* __restrict__ f, const float4* __restrict__ z,
    const float4* __restrict__ ig, const float4* __restrict__ Hs,
    float4* __restrict__ out) {
  constexpr int CL = T / NC;
  static_assert(CL % U == 0, "");
  const int c4    = blockIdx.x * 256 + threadIdx.x;
  const int chunk = blockIdx.y;
  int idx = chunk * CL * C4 + c4;
  float4 h = Hs[chunk * C4 + c4];
  v4f* __restrict__ outv = (v4f*)out;
  for (int body = 0; body < CL / U; ++body) {
    float4 rf[U], rz[U], ri[U];
#pragma unroll
    for (int u = 0; u < U; ++u) {
      rf[u] = f[idx + u * C4];
      rz[u] = z[idx + u * C4];
      ri[u] = ig[idx + u * C4];
    }
#pragma unroll
    for (int u = 0; u < U; ++u) {
      fma4(h, rf[u], rz[u], ri[u]);
      // nontemporal: out is never re-read; keep f/z/i resident in LLC instead.
      v4f hv = {h.x, h.y, h.z, h.w};
      __builtin_nontemporal_store(hv, &outv[idx + u * C4]);
    }
    idx += U * C4;
  }
}

template <int NC, int U>
static void launch_all(const float4* f, const float4* z, const float4* ig,
                       const float4* hinit, float4* out, void* ws,
                       hipStream_t stream) {
  float4* Ps = (float4*)ws;
  float4* Hs = (float4*)((char*)ws + (size_t)NC * CHN * sizeof(float));
  dim3 blk(256);
  dim3 g13(C4 / 256, NC);
  dim3 g2(C4 / 256);
  qrnn_partial<NC, U><<<g13, blk, 0, stream>>>(f, z, ig, Ps, Hs);
  qrnn_scan<NC><<<g2, blk, 0, stream>>>(hinit, Ps, Hs);
  qrnn_final<NC, U><<<g13, blk, 0, stream>>>(f, z, ig, Hs, out);
}

extern "C" void kernel_launch(void* const* d_in, const int* in_sizes, int n_in,
                              void* d_out, int out_size, void* d_ws, size_t ws_size,
                              hipStream_t stream) {
  const float4* f     = (const float4*)d_in[0];
  const float4* z     = (const float4*)d_in[1];
  const float4* ig    = (const float4*)d_in[2];
  const float4* hinit = (const float4*)d_in[3];
  float4* out = (float4*)d_out;

  auto need = [](int nc) { return 2ull * nc * CHN * sizeof(float); };
  if (ws_size >= need(256)) {
    launch_all<256, 2>(f, z, ig, hinit, out, d_ws, stream);   // 16 MiB ws, 32 waves/CU
  } else if (ws_size >= need(64)) {
    launch_all<64, 2>(f, z, ig, hinit, out, d_ws, stream);    // 4 MiB ws
  } else {
    launch_all<16, 2>(f, z, ig, hinit, out, d_ws, stream);    // 1 MiB ws
  }
}

// Round 8
// 207.204 us; speedup vs baseline: 1.2758x; 1.2758x over previous
//
#include <hip/hip_runtime.h>

// QRNN forget-mult: h_t = i_t*z_t + f_t*h_{t-1}, T=4096, B=32, H=256, fp32.
// Chunked parallel scan over T.
// Round 8 model (from R4/R6/R7): effective loaded mem latency ~2-4us; BW =
// bytes-in-flight / latency. R6 had MLP but 8 waves/CU (grid=512); R7 had 23
// waves/CU but VGPR=32 killed MLP. Need BOTH: NC=128 -> 1024 blocks (16
// waves/CU at <=128 VGPR) AND U=8 batched loads (24 float4 = 96 VGPR payload
// actually resident under __launch_bounds__(256,4)). ~384 KB/CU in flight.

constexpr int T   = 4096;
constexpr int CHN = 32 * 256;   // 8192 channels (B*H)
constexpr int C4  = CHN / 4;    // 2048 float4-channels

typedef float v4f __attribute__((ext_vector_type(4)));

__device__ __forceinline__ void fma4(float4& h, const float4& ft, const float4& zt,
                                     const float4& it) {
  h.x = fmaf(ft.x, h.x, it.x * zt.x);
  h.y = fmaf(ft.y, h.y, it.y * zt.y);
  h.z = fmaf(ft.z, h.z, it.z * zt.z);
  h.w = fmaf(ft.w, h.w, it.w * zt.w);
}

// ---------------- kernel 1: per-chunk local recurrence + forget product ----------------
template <int NC, int U>
__global__ __launch_bounds__(256, 4) void qrnn_partial(
    const float4* __restrict__ f, const float4* __restrict__ z,
    const float4* __restrict__ ig,
    float4* __restrict__ Ps, float4* __restrict__ Hs) {
  constexpr int CL = T / NC;
  static_assert(CL % U == 0, "");
  const int c4    = blockIdx.x * 256 + threadIdx.x;
  const int chunk = blockIdx.y;
  int idx = chunk * CL * C4 + c4;
  float4 h = make_float4(0.f, 0.f, 0.f, 0.f);
  float4 P = make_float4(1.f, 1.f, 1.f, 1.f);
  for (int body = 0; body < CL / U; ++body) {
    float4 rf[U], rz[U], ri[U];
#pragma unroll
    for (int u = 0; u < U; ++u) rf[u] = f[idx + u * C4];
#pragma unroll
    for (int u = 0; u < U; ++u) rz[u] = z[idx + u * C4];
#pragma unroll
    for (int u = 0; u < U; ++u) ri[u] = ig[idx + u * C4];
#pragma unroll
    for (int u = 0; u < U; ++u) {
      fma4(h, rf[u], rz[u], ri[u]);
      P.x *= rf[u].x; P.y *= rf[u].y; P.z *= rf[u].z; P.w *= rf[u].w;
    }
    idx += U * C4;
  }
  Ps[chunk * C4 + c4] = P;
  Hs[chunk * C4 + c4] = h;
}

// ---------------- kernel 2: sequential scan over chunk summaries ----------------
// After this kernel, Hs[k] holds the hidden state ENTERING chunk k.
// Latency-bound (8 blocks): batch US loads per round trip.
template <int NC>
__global__ __launch_bounds__(256) void qrnn_scan(
    const float4* __restrict__ hinit,
    const float4* __restrict__ Ps, float4* __restrict__ Hs) {
  const int c4 = blockIdx.x * 256 + threadIdx.x;
  float4 carry = hinit[c4];
  constexpr int US = 16;
  static_assert(NC % US == 0, "");
  for (int k0 = 0; k0 < NC; k0 += US) {
    float4 rp[US], rh[US];
#pragma unroll
    for (int u = 0; u < US; ++u) rp[u] = Ps[(k0 + u) * C4 + c4];
#pragma unroll
    for (int u = 0; u < US; ++u) rh[u] = Hs[(k0 + u) * C4 + c4];
#pragma unroll
    for (int u = 0; u < US; ++u) {
      Hs[(k0 + u) * C4 + c4] = carry;
      carry.x = fmaf(rp[u].x, carry.x, rh[u].x);
      carry.y = fmaf(rp[u].y, carry.y, rh[u].y);
      carry.z = fmaf(rp[u].z, carry.z, rh[u].z);
      carry.w = fmaf(rp[u].w, carry.w, rh[u].w);
    }
  }
}

// ---------------- kernel 3: recompute chunk from exact carry, write output ----------------
template <int NC, int U>
__global__ __launch_bounds__(256, 4) void qrnn_final(
    const float4* __restrict__ f, const float4* __restrict__ z,
    const float4* __restrict__ ig, const float4* __restrict__ Hs,
    float4* __restrict__ out) {
  constexpr int CL = T / NC;
  static_assert(CL % U == 0, "");
  const int c4    = blockIdx.x * 256 + threadIdx.x;
  const int chunk = blockIdx.y;
  int idx = chunk * CL * C4 + c4;
  float4 h = Hs[chunk * C4 + c4];
  v4f* __restrict__ outv = (v4f*)out;
  for (int body = 0; body < CL / U; ++body) {
    float4 rf[U], rz[U], ri[U];
#pragma unroll
    for (int u = 0; u < U; ++u) rf[u] = f[idx + u * C4];
#pragma unroll
    for (int u = 0; u < U; ++u) rz[u] = z[idx + u * C4];
#pragma unroll
    for (int u = 0; u < U; ++u) ri[u] = ig[idx + u * C4];
#pragma unroll
    for (int u = 0; u < U; ++u) {
      fma4(h, rf[u], rz[u], ri[u]);
      // nontemporal: out is never re-read; keep f/z/i resident in LLC instead.
      v4f hv = {h.x, h.y, h.z, h.w};
      __builtin_nontemporal_store(hv, &outv[idx + u * C4]);
    }
    idx += U * C4;
  }
}

template <int NC, int U>
static void launch_all(const float4* f, const float4* z, const float4* ig,
                       const float4* hinit, float4* out, void* ws,
                       hipStream_t stream) {
  float4* Ps = (float4*)ws;
  float4* Hs = (float4*)((char*)ws + (size_t)NC * CHN * sizeof(float));
  dim3 blk(256);
  dim3 g13(C4 / 256, NC);
  dim3 g2(C4 / 256);
  qrnn_partial<NC, U><<<g13, blk, 0, stream>>>(f, z, ig, Ps, Hs);
  qrnn_scan<NC><<<g2, blk, 0, stream>>>(hinit, Ps, Hs);
  qrnn_final<NC, U><<<g13, blk, 0, stream>>>(f, z, ig, Hs, out);
}

extern "C" void kernel_launch(void* const* d_in, const int* in_sizes, int n_in,
                              void* d_out, int out_size, void* d_ws, size_t ws_size,
                              hipStream_t stream) {
  const float4* f     = (const float4*)d_in[0];
  const float4* z     = (const float4*)d_in[1];
  const float4* ig    = (const float4*)d_in[2];
  const float4* hinit = (const float4*)d_in[3];
  float4* out = (float4*)d_out;

  auto need = [](int nc) { return 2ull * nc * CHN * sizeof(float); };
  if (ws_size >= need(128)) {
    launch_all<128, 8>(f, z, ig, hinit, out, d_ws, stream);   // 8 MiB ws
  } else if (ws_size >= need(64)) {
    launch_all<64, 8>(f, z, ig, hinit, out, d_ws, stream);    // 4 MiB ws
  } else {
    launch_all<16, 8>(f, z, ig, hinit, out, d_ws, stream);    // 1 MiB ws
  }
}